// Round 1
// baseline (1127.230 us; speedup 1.0000x reference)
//
#include <hip/hip_runtime.h>

#define MAX_ITER 8192
#define NCHUNK   64
#define NCHUNKS  128          // MAX_ITER / NCHUNK
#define NSCAN    64           // scanner blocks, 1 sample each
#define NTHREADS 256
#define MAGIC    0x13572468u

typedef unsigned long long u64;
#define KEY_MAX 0xffffffffffffffffull

// IEEE fp32 ops, contraction off -> bitwise numpy match (verified rounds 2-7).
__device__ __forceinline__ float mul_rn(float a, float b) {
#pragma clang fp contract(off)
  return a * b;
}
__device__ __forceinline__ float add_rn(float a, float b) {
#pragma clang fp contract(off)
  return a + b;
}
__device__ __forceinline__ float sub_rn(float a, float b) {
#pragma clang fp contract(off)
  return a - b;
}
__device__ __forceinline__ float bcastf(float v, int lane) {
  return __int_as_float(__builtin_amdgcn_readlane(__float_as_int(v), lane));
}
__device__ __forceinline__ void st_agent(u64* p, u64 v) {
  __hip_atomic_store(p, v, __ATOMIC_RELAXED, __HIP_MEMORY_SCOPE_AGENT);
}
__device__ __forceinline__ u64 ld_agent(u64* p) {
  return __hip_atomic_load(p, __ATOMIC_RELAXED, __HIP_MEMORY_SCOPE_AGENT);
}
__device__ __forceinline__ void st_agent32(unsigned* p, unsigned v) {
  __hip_atomic_store(p, v, __ATOMIC_RELAXED, __HIP_MEMORY_SCOPE_AGENT);
}
__device__ __forceinline__ unsigned ld_agent32(unsigned* p) {
  return __hip_atomic_load(p, __ATOMIC_RELAXED, __HIP_MEMORY_SCOPE_AGENT);
}
__device__ __forceinline__ u64 packf2(float x, float y) {
  return ((u64)__float_as_uint(y) << 32) | (u64)__float_as_uint(x);
}
__device__ __forceinline__ void waitcnt_vm0() {
  asm volatile("s_waitcnt vmcnt(0)" ::: "memory");
}
__device__ __forceinline__ void compiler_fence() {
  asm volatile("" ::: "memory");
}
// Exact (d2, idx) lexicographic key (scanners only): d2 >= 0 -> bit-monotonic.
__device__ __forceinline__ u64 mkkey(float d2, int idx) {
  return ((u64)__float_as_uint(d2) << 32) | (u64)(unsigned)idx;
}

__global__ __launch_bounds__(NTHREADS) void rrt_kernel(
    const float* __restrict__ state, const float* __restrict__ goal,
    const float* __restrict__ u, const float* __restrict__ r,
    float* __restrict__ out, unsigned* __restrict__ ws) {
  // scanners: nodes 1..8064 staged from outU.  coordinator (block 0): its OWN
  // copy of nodes 1..8064 (written as produced) so the winning M-index resolves
  // via ~100cyc ds_read instead of a ~600cyc L3 MbufC load.
  __shared__ __align__(16) float2 nodesL[8064];
  __shared__ u64 sharedK[4];

  u64* outU = (u64*)out;                // node i at outU[i] (float2-packed)
  unsigned* nflag = ws;                 // coordinator epoch       (byte 0)
  unsigned* ini   = ws + 32;            // init guard              (byte 128)
  u64* MbufK = (u64*)(ws + 64);         // 64 tagged keys          (byte 256)
  // (MbufC slot no longer used: key idx + LDS lookup replaces it)

  const int tid  = threadIdx.x;
  const int wave = tid >> 6;
  const int lane = tid & 63;
  const int blk  = blockIdx.x;

  const float n0x = state[0], n0y = state[1];
  const float gx = goal[0],  gy = goal[1];

  if (blk == 0) {
    // ================= coordinator: one wave, no barriers ==================
    if (tid == 0) {   // d_ws re-poisoned 0xAA each launch: poison tag = 85 != first-read epoch 1
      st_agent32(nflag, 0u);
      st_agent(&outU[0], packf2(n0x, n0y));   // node 0
      waitcnt_vm0();
      st_agent32(ini, MAGIC);
    }
    if (tid >= 64) return;

    // current-chunk sample (chunk 0)
    float sx, sy;
    {
      const float uu = u[lane];
      if (uu < 0.1f) { sx = gx; sy = gy; }
      else { sx = mul_rn(r[2 * lane], 200.0f); sy = mul_rn(r[2 * lane + 1], 200.0f); }
    }
    float cbd2 = 3.0e38f, cbx = 0.0f, cby = 0.0f;   // carry over (c-64, c]
    u64 kvPre = 0;                                   // speculative MbufK preload

    for (int k = 0; k < NCHUNKS; ++k) {
      const int c = k * NCHUNK;
      const bool hasNext = (k < NCHUNKS - 1);

      // prefetch next-chunk sample before the tag check (independent L2 loads)
      float nsx = 0.0f, nsy = 0.0f;
      if (hasNext) {
        const int i2 = c + NCHUNK + lane;
        const float uu = u[i2];
        if (uu < 0.1f) { nsx = gx; nsy = gy; }
        else { nsx = mul_rn(r[2 * i2], 200.0f); nsy = mul_rn(r[2 * i2 + 1], 200.0f); }
      }

      // ---- assemble argmin over [0..c]: scanner M [0..c-64] + carry (c-64,c]
      float bd2, bx, by;
      if (k == 0) {
        const float dx = sub_rn(n0x, sx), dy = sub_rn(n0y, sy);
        bd2 = add_rn(mul_rn(dx, dx), mul_rn(dy, dy));
        bx = n0x; by = n0y;
      } else {
        u64 kv = kvPre;   // loaded before last chunk's vmcnt(0) drain
        if (!__all((int)(((unsigned)kv >> 13) & 0x7Fu) == k)) {
          for (;;) {   // tag-in-key poll: one coalesced load, all 64 must match k
            kv = ld_agent(&MbufK[lane]);
            if (__all((int)(((unsigned)kv >> 13) & 0x7Fu) == k)) break;
            __builtin_amdgcn_s_sleep(1);
          }
        }
        compiler_fence();
        const float md2 = __uint_as_float((unsigned)(kv >> 32));
        const unsigned midx = (unsigned)kv & 0x1FFFu;
        bd2 = cbd2; bx = cbx; by = cby;
        if (!(bd2 < md2)) {   // M's indices are all lower: M wins ties
          bd2 = md2;
          if (midx == 0u) { bx = n0x; by = n0y; }
          else { const float2 p = nodesL[midx - 1]; bx = p.x; by = p.y; }
        }
      }

      // pre-steer (round-3-verified math)
      float nx, ny;
      {
        const float dirx = sub_rn(sx, bx), diry = sub_rn(sy, by);
        const float dist = __fsqrt_rn(add_rn(bd2, 1e-12f));
        const float scl = (dist > 5.0f) ? __fdiv_rn(5.0f, dist) : 1.0f;
        nx = add_rn(bx, mul_rn(dirx, scl));
        ny = add_rn(by, mul_rn(diry, scl));
      }

      float nbd2 = 3.0e38f, nbx = 0.0f, nby = 0.0f;   // next carry

      // ---- 64 steps in groups of 8: speculative batched broadcasts.
      // Broadcasts are stale only if a lane INSIDE the group window would be
      // updated by one of the group's nodes; detected conservatively via
      // min(nd2[0..7]) < bd2_entry (bd2 only decreases -> superset of updates).
      #pragma unroll
      for (int g = 0; g < NCHUNK; g += 8) {
        float qx[8], qy[8], da[8];
        #pragma unroll
        for (int j = 0; j < 8; ++j) {
          qx[j] = bcastf(nx, g + j);   // node c+g+j+1 (speculative)
          qy[j] = bcastf(ny, g + j);
        }
        #pragma unroll
        for (int j = 0; j < 8; ++j) {
          const float dx = sub_rn(qx[j], sx), dy = sub_rn(qy[j], sy);
          da[j] = add_rn(mul_rn(dx, dx), mul_rn(dy, dy));
        }
        const float m8 = fminf(fminf(fminf(da[0], da[1]), fminf(da[2], da[3])),
                               fminf(fminf(da[4], da[5]), fminf(da[6], da[7])));
        const bool cond = (m8 < bd2);

        if (__builtin_expect(__any((int)(cond && lane > g && lane < g + 8)), 0)) {
          // ---- danger: exact sequential replay of steps g..g+7 (rare) ----
          #pragma unroll
          for (int j = 0; j < 8; ++j) {
            const int t = g + j;
            const float px = bcastf(nx, t);
            const float py = bcastf(ny, t);
            if (lane > t) {
              const float dx = sub_rn(px, sx), dy = sub_rn(py, sy);
              const float nd2 = add_rn(mul_rn(dx, dx), mul_rn(dy, dy));
              if (nd2 < bd2) {
                bd2 = nd2; bx = px; by = py;
                const float dirx = sub_rn(sx, bx), diry = sub_rn(sy, by);
                const float dist = __fsqrt_rn(add_rn(nd2, 1e-12f));
                const float scl = (dist > 5.0f) ? __fdiv_rn(5.0f, dist) : 1.0f;
                nx = add_rn(bx, mul_rn(dirx, scl));
                ny = add_rn(by, mul_rn(diry, scl));
              }
            }
            const float dxb = sub_rn(px, nsx), dyb = sub_rn(py, nsy);
            const float ndb = add_rn(mul_rn(dxb, dxb), mul_rn(dyb, dyb));
            if (ndb < nbd2) { nbd2 = ndb; nbx = px; nby = py; }
          }
        } else {
          // ---- fast path: broadcasts valid; lanes >= g+8 fold updates ----
          const bool apply = cond && (lane >= g + 8);
          if (__builtin_expect(__any((int)apply), 0)) {
            if (apply) {
              #pragma unroll
              for (int j = 0; j < 8; ++j) {   // ascending strict <: exact ties
                if (da[j] < bd2) { bd2 = da[j]; bx = qx[j]; by = qy[j]; }
              }
              // steer depends only on final (bd2,bx,by): one recompute, same bits
              const float dirx = sub_rn(sx, bx), diry = sub_rn(sy, by);
              const float dist = __fsqrt_rn(add_rn(bd2, 1e-12f));
              const float scl = (dist > 5.0f) ? __fdiv_rn(5.0f, dist) : 1.0f;
              nx = add_rn(bx, mul_rn(dirx, scl));
              ny = add_rn(by, mul_rn(diry, scl));
            }
          }
          // carried next-chunk fold over the 8 validated nodes (all lanes)
          #pragma unroll
          for (int j = 0; j < 8; ++j) {
            const float dxb = sub_rn(qx[j], nsx), dyb = sub_rn(qy[j], nsy);
            const float ndb = add_rn(mul_rn(dxb, dxb), mul_rn(dyb, dyb));
            if (ndb < nbd2) { nbd2 = ndb; nbx = qx[j]; nby = qy[j]; }
          }
        }
      }

      // publish: LDS self-copy (for later M-index resolution) + global nodes
      if (c + lane < 8064) {
        float2 p; p.x = nx; p.y = ny;
        nodesL[c + lane] = p;             // node c+lane+1 at LDS idx c+lane
      }
      st_agent(&outU[c + lane + 1], packf2(nx, ny));
      if (hasNext) kvPre = ld_agent(&MbufK[lane]);   // speculative: hides poll
      waitcnt_vm0();                     // wave-level drain of stores (+preload)
      if (lane == 0 && hasNext) st_agent32(nflag, (unsigned)(k + 1));

      cbd2 = nbd2; cbx = nbx; cby = nby;
      sx = nsx; sy = nsy;
    }
  } else {
    // ================= scanners: blocks 1..64, one sample each =============
    const int b = blk - 1;
    if (tid == 0) {
      while (ld_agent32(ini) != MAGIC) __builtin_amdgcn_s_sleep(2);
      compiler_fence();
    }
    __syncthreads();

    for (int k = 0; k < NCHUNKS - 1; ++k) {   // iter k -> M_{k+1} over [0..64k]
      const int c = k * NCHUNK;

      // my sample: chunk k+1, slot b — flag-independent, issue before the poll
      float sx, sy;
      {
        const int i = (k + 1) * NCHUNK + b;
        const float uu = u[i];
        if (uu < 0.1f) { sx = gx; sy = gy; }
        else { sx = mul_rn(r[2 * i], 200.0f); sy = mul_rn(r[2 * i + 1], 200.0f); }
      }

      if (k >= 1 && wave == 0) {   // poll epoch k; pull newest 64 nodes
        while (ld_agent32(nflag) < (unsigned)k) __builtin_amdgcn_s_sleep(1);
        compiler_fence();
        const int j = c - NCHUNK + 1 + lane;   // nodes (c-64, c]
        const u64 nv = ld_agent(&outU[j]);
        float2 p;
        p.x = __uint_as_float((unsigned)(nv & 0xffffffffu));
        p.y = __uint_as_float((unsigned)(nv >> 32));
        nodesL[j - 1] = p;
      }
      __syncthreads();

      u64 key = KEY_MAX;
      if (tid == 0) {   // node 0
        const float dx = sub_rn(n0x, sx), dy = sub_rn(n0y, sy);
        key = mkkey(add_rn(mul_rn(dx, dx), mul_rn(dy, dy)), 0);
      }
      // 256 lanes stride node pairs; float4 = nodes (j, j+1), j odd
      for (int j = 1 + 2 * tid; j < c; j += 2 * NTHREADS) {
        const float4 p = *(const float4*)&nodesL[j - 1];
        const float dxa = sub_rn(p.x, sx), dya = sub_rn(p.y, sy);
        const u64 ka = mkkey(add_rn(mul_rn(dxa, dxa), mul_rn(dya, dya)), j);
        const float dxb = sub_rn(p.z, sx), dyb = sub_rn(p.w, sy);
        const u64 kb = mkkey(add_rn(mul_rn(dxb, dxb), mul_rn(dyb, dyb)), j + 1);
        if (ka < key) key = ka;     // lower idx first: exact argmin ties
        if (kb < key) key = kb;
      }
      #pragma unroll
      for (int m = 32; m >= 1; m >>= 1) {
        const u64 ok = __shfl_xor(key, m, 64);
        if (ok < key) key = ok;
      }
      if (lane == 0) sharedK[wave] = key;
      __syncthreads();

      if (wave == 0) {
        u64 kk = (lane < 4) ? sharedK[lane] : KEY_MAX;
        u64 ok = __shfl_xor(kk, 1, 64); if (ok < kk) kk = ok;
        ok = __shfl_xor(kk, 2, 64);     if (ok < kk) kk = ok;
        if (lane == 0) {
          // single self-validating publish: (d2 | tag | idx); coords resolved
          // by the coordinator from its own LDS node copy
          st_agent(&MbufK[b], kk | ((u64)(unsigned)(k + 1) << 13));
        }
      }
      // next iter's LDS writes (nodes (c, c+64]) are disjoint from this iter's
      // reads and gated by the top-of-loop __syncthreads.
    }
  }
}

extern "C" void kernel_launch(void* const* d_in, const int* in_sizes, int n_in,
                              void* d_out, int out_size, void* d_ws, size_t ws_size,
                              hipStream_t stream) {
  const float* state = (const float*)d_in[0];
  const float* goal  = (const float*)d_in[1];
  const float* u     = (const float*)d_in[2];
  const float* r     = (const float*)d_in[3];
  float* out = (float*)d_out;
  unsigned* ws = (unsigned*)d_ws;
  (void)in_sizes; (void)n_in; (void)out_size; (void)ws_size;
  rrt_kernel<<<NSCAN + 1, NTHREADS, 0, stream>>>(state, goal, u, r, out, ws);
}

// Round 2
// 1119.753 us; speedup vs baseline: 1.0067x; 1.0067x over previous
//
#include <hip/hip_runtime.h>

#define MAX_ITER 8192
#define NCHUNK   64
#define NCHUNKS  128          // MAX_ITER / NCHUNK
#define NSCAN    64           // scanner blocks, 1 sample each
#define NTHREADS 256
#define MAGIC    0x13572468u

typedef unsigned long long u64;
#define KEY_MAX 0xffffffffffffffffull

// IEEE fp32 ops, contraction off -> bitwise numpy match (verified rounds 2-7).
__device__ __forceinline__ float mul_rn(float a, float b) {
#pragma clang fp contract(off)
  return a * b;
}
__device__ __forceinline__ float add_rn(float a, float b) {
#pragma clang fp contract(off)
  return a + b;
}
__device__ __forceinline__ float sub_rn(float a, float b) {
#pragma clang fp contract(off)
  return a - b;
}
__device__ __forceinline__ float bcastf(float v, int lane) {
  return __int_as_float(__builtin_amdgcn_readlane(__float_as_int(v), lane));
}
__device__ __forceinline__ void st_agent(u64* p, u64 v) {
  __hip_atomic_store(p, v, __ATOMIC_RELAXED, __HIP_MEMORY_SCOPE_AGENT);
}
__device__ __forceinline__ u64 ld_agent(u64* p) {
  return __hip_atomic_load(p, __ATOMIC_RELAXED, __HIP_MEMORY_SCOPE_AGENT);
}
__device__ __forceinline__ void st_agent32(unsigned* p, unsigned v) {
  __hip_atomic_store(p, v, __ATOMIC_RELAXED, __HIP_MEMORY_SCOPE_AGENT);
}
__device__ __forceinline__ unsigned ld_agent32(unsigned* p) {
  return __hip_atomic_load(p, __ATOMIC_RELAXED, __HIP_MEMORY_SCOPE_AGENT);
}
__device__ __forceinline__ u64 packf2(float x, float y) {
  return ((u64)__float_as_uint(y) << 32) | (u64)__float_as_uint(x);
}
__device__ __forceinline__ void waitcnt_vm0() {
  asm volatile("s_waitcnt vmcnt(0)" ::: "memory");
}
__device__ __forceinline__ void compiler_fence() {
  asm volatile("" ::: "memory");
}
// Exact (d2, idx) lexicographic key: d2 >= 0 -> bit-monotonic; ties -> low idx.
__device__ __forceinline__ u64 mkkey(float d2, int idx) {
  return ((u64)__float_as_uint(d2) << 32) | (u64)(unsigned)idx;
}

__global__ __launch_bounds__(NTHREADS) void rrt_kernel(
    const float* __restrict__ state, const float* __restrict__ goal,
    const float* __restrict__ u, const float* __restrict__ r,
    float* __restrict__ out, unsigned* __restrict__ ws) {
  // scanners: nodes staged from outU.  coordinator (block 0): its OWN copy of
  // nodes (written as produced) so the winning M-index resolves via ds_read.
  __shared__ __align__(16) float2 nodesL[8064];
  __shared__ u64 sharedK[4];

  u64* outU = (u64*)out;                // node i at outU[i] (float2-packed)
  unsigned* nflag = ws;                 // coordinator epoch       (byte 0)
  unsigned* ini   = ws + 32;            // init guard              (byte 128)
  u64* MbufK = (u64*)(ws + 64);         // 64 tagged keys          (byte 256)

  const int tid  = threadIdx.x;
  const int wave = tid >> 6;
  const int lane = tid & 63;
  const int blk  = blockIdx.x;

  const float n0x = state[0], n0y = state[1];
  const float gx = goal[0],  gy = goal[1];

  if (blk == 0) {
    // ================= coordinator: one wave, no barriers ==================
    if (tid == 0) {   // d_ws re-poisoned 0xAA each launch: poison tag = 85 != any first-read tag (1..4)
      st_agent32(nflag, 0u);
      st_agent(&outU[0], packf2(n0x, n0y));   // node 0
      waitcnt_vm0();
      st_agent32(ini, MAGIC);
    }
    if (tid >= 64) return;

    // current-chunk sample (chunk 0)
    float sx, sy;
    {
      const float uu = u[lane];
      if (uu < 0.1f) { sx = gx; sy = gy; }
      else { sx = mul_rn(r[2 * lane], 200.0f); sy = mul_rn(r[2 * lane + 1], 200.0f); }
    }
    float cbd2 = 3.0e38f, cbx = 0.0f, cby = 0.0f;   // carry over (c-64, c]
    u64 kvPre = 0;                                   // speculative MbufK preload

    for (int k = 0; k < NCHUNKS; ++k) {
      const int c = k * NCHUNK;
      const bool hasNext = (k < NCHUNKS - 1);

      // prefetch next-chunk sample before the tag check (independent L2 loads;
      // also hides the in-flight kvPre load issued at end of previous chunk)
      float nsx = 0.0f, nsy = 0.0f;
      if (hasNext) {
        const int i2 = c + NCHUNK + lane;
        const float uu = u[i2];
        if (uu < 0.1f) { nsx = gx; nsy = gy; }
        else { nsx = mul_rn(r[2 * i2], 200.0f); nsy = mul_rn(r[2 * i2 + 1], 200.0f); }
      }

      // ---- assemble argmin over [0..c]: scanner M [0..c-64] + carry (c-64,c]
      float bd2, bx, by;
      if (k == 0) {
        const float dx = sub_rn(n0x, sx), dy = sub_rn(n0y, sy);
        bd2 = add_rn(mul_rn(dx, dx), mul_rn(dy, dy));
        bx = n0x; by = n0y;
      } else {
        u64 kv = kvPre;   // loaded after previous chunk's nflag store
        if (!__all((int)(((unsigned)kv >> 13) & 0x7Fu) == k)) {
          for (;;) {   // tag-in-key poll: one coalesced load, all 64 must match k
            kv = ld_agent(&MbufK[lane]);
            if (__all((int)(((unsigned)kv >> 13) & 0x7Fu) == k)) break;
            __builtin_amdgcn_s_sleep(1);
          }
        }
        compiler_fence();
        const float md2 = __uint_as_float((unsigned)(kv >> 32));
        const unsigned midx = (unsigned)kv & 0x1FFFu;
        bd2 = cbd2; bx = cbx; by = cby;
        if (!(bd2 < md2)) {   // M's indices are all lower: M wins ties
          bd2 = md2;
          if (midx == 0u) { bx = n0x; by = n0y; }
          else { const float2 p = nodesL[midx - 1]; bx = p.x; by = p.y; }
        }
      }

      // pre-steer (round-3-verified math)
      float nx, ny;
      {
        const float dirx = sub_rn(sx, bx), diry = sub_rn(sy, by);
        const float dist = __fsqrt_rn(add_rn(bd2, 1e-12f));
        const float scl = (dist > 5.0f) ? __fdiv_rn(5.0f, dist) : 1.0f;
        nx = add_rn(bx, mul_rn(dirx, scl));
        ny = add_rn(by, mul_rn(diry, scl));
      }

      float nbd2 = 3.0e38f, nbx = 0.0f, nby = 0.0f;   // next carry

      // ---- 64 steps in groups of 8: speculative batched broadcasts.
      // Broadcasts are stale only if a lane INSIDE the group window would be
      // updated by one of the group's nodes; the first such update always uses
      // valid data and satisfies min(da) < bd2_entry -> conservatively caught.
      #pragma unroll
      for (int g = 0; g < NCHUNK; g += 8) {
        float qx[8], qy[8], da[8];
        #pragma unroll
        for (int j = 0; j < 8; ++j) {
          qx[j] = bcastf(nx, g + j);   // node c+g+j+1 (speculative)
          qy[j] = bcastf(ny, g + j);
        }
        #pragma unroll
        for (int j = 0; j < 8; ++j) {
          const float dx = sub_rn(qx[j], sx), dy = sub_rn(qy[j], sy);
          da[j] = add_rn(mul_rn(dx, dx), mul_rn(dy, dy));
        }
        const float m8 = fminf(fminf(fminf(da[0], da[1]), fminf(da[2], da[3])),
                               fminf(fminf(da[4], da[5]), fminf(da[6], da[7])));
        const bool cond = (m8 < bd2);

        if (__builtin_expect(__any((int)(cond && lane > g && lane < g + 8)), 0)) {
          // ---- danger: exact sequential replay of steps g..g+7 (rare) ----
          #pragma unroll
          for (int j = 0; j < 8; ++j) {
            const int t = g + j;
            const float px = bcastf(nx, t);
            const float py = bcastf(ny, t);
            if (lane > t) {
              const float dx = sub_rn(px, sx), dy = sub_rn(py, sy);
              const float nd2 = add_rn(mul_rn(dx, dx), mul_rn(dy, dy));
              if (nd2 < bd2) {
                bd2 = nd2; bx = px; by = py;
                const float dirx = sub_rn(sx, bx), diry = sub_rn(sy, by);
                const float dist = __fsqrt_rn(add_rn(nd2, 1e-12f));
                const float scl = (dist > 5.0f) ? __fdiv_rn(5.0f, dist) : 1.0f;
                nx = add_rn(bx, mul_rn(dirx, scl));
                ny = add_rn(by, mul_rn(diry, scl));
              }
            }
            const float dxb = sub_rn(px, nsx), dyb = sub_rn(py, nsy);
            const float ndb = add_rn(mul_rn(dxb, dxb), mul_rn(dyb, dyb));
            if (ndb < nbd2) { nbd2 = ndb; nbx = px; nby = py; }
          }
        } else {
          // ---- fast path: broadcasts valid; lanes >= g+8 fold updates ----
          const bool apply = cond && (lane >= g + 8);
          if (__builtin_expect(__any((int)apply), 0)) {
            if (apply) {
              #pragma unroll
              for (int j = 0; j < 8; ++j) {   // ascending strict <: exact ties
                if (da[j] < bd2) { bd2 = da[j]; bx = qx[j]; by = qy[j]; }
              }
              // steer depends only on final (bd2,bx,by): one recompute, same bits
              const float dirx = sub_rn(sx, bx), diry = sub_rn(sy, by);
              const float dist = __fsqrt_rn(add_rn(bd2, 1e-12f));
              const float scl = (dist > 5.0f) ? __fdiv_rn(5.0f, dist) : 1.0f;
              nx = add_rn(bx, mul_rn(dirx, scl));
              ny = add_rn(by, mul_rn(diry, scl));
            }
          }
          // carried next-chunk fold over the 8 validated nodes (all lanes)
          #pragma unroll
          for (int j = 0; j < 8; ++j) {
            const float dxb = sub_rn(qx[j], nsx), dyb = sub_rn(qy[j], nsy);
            const float ndb = add_rn(mul_rn(dxb, dxb), mul_rn(dyb, dyb));
            if (ndb < nbd2) { nbd2 = ndb; nbx = qx[j]; nby = qy[j]; }
          }
        }
      }

      // publish: LDS self-copy (for later M-index resolution) + global nodes
      if (c + lane < 8064) {
        float2 p; p.x = nx; p.y = ny;
        nodesL[c + lane] = p;             // node c+lane+1 at LDS idx c+lane
      }
      st_agent(&outU[c + lane + 1], packf2(nx, ny));
      waitcnt_vm0();                     // drain ONLY the node stores (+samples)
      if (lane == 0 && hasNext) st_agent32(nflag, (unsigned)(k + 1));
      compiler_fence();
      // speculative preload AFTER nflag: off the drain path; latency hides
      // under next chunk's sample prefetch. Stale -> poll fallback.
      if (hasNext) kvPre = ld_agent(&MbufK[lane]);

      cbd2 = nbd2; cbx = nbx; cby = nby;
      sx = nsx; sy = nsy;
    }
  } else {
    // ================= scanners: blocks 1..64, one sample each =============
    // Iter k publishes M tagged k+1 over [0..64k]:
    //   bulk [1..64(k-1)] from LDS (present from prior iters) BEFORE the poll,
    //   then wave 0 polls nflag>=k, loads the 64 fresh nodes (1/lane), folds
    //   one distance each, re-reduces, publishes.  Post-nflag response chain
    //   is poll + 64-node load + 1 dist + reduce + store (~1.5us), not a full
    //   8K-node rescan (~4us).
    const int b = blk - 1;
    if (tid == 0) {
      while (ld_agent32(ini) != MAGIC) __builtin_amdgcn_s_sleep(2);
      compiler_fence();
    }
    __syncthreads();

    for (int k = 0; k < NCHUNKS - 1; ++k) {
      const int c  = k * NCHUNK;
      const int cb = c - NCHUNK;        // bulk top: nodes [1..cb] are in LDS

      // my sample: chunk k+1, slot b
      float sx, sy;
      {
        const int i = (k + 1) * NCHUNK + b;
        const float uu = u[i];
        if (uu < 0.1f) { sx = gx; sy = gy; }
        else { sx = mul_rn(r[2 * i], 200.0f); sy = mul_rn(r[2 * i + 1], 200.0f); }
      }

      // ---- bulk scan (no dependence on current epoch) ----
      u64 key = KEY_MAX;
      if (tid == 0) {   // node 0
        const float dx = sub_rn(n0x, sx), dy = sub_rn(n0y, sy);
        key = mkkey(add_rn(mul_rn(dx, dx), mul_rn(dy, dy)), 0);
      }
      // 256 lanes stride node pairs; float4 = nodes (j, j+1), j odd
      for (int j = 1 + 2 * tid; j < cb; j += 2 * NTHREADS) {
        const float4 p = *(const float4*)&nodesL[j - 1];
        const float dxa = sub_rn(p.x, sx), dya = sub_rn(p.y, sy);
        const u64 ka = mkkey(add_rn(mul_rn(dxa, dxa), mul_rn(dya, dya)), j);
        const float dxb = sub_rn(p.z, sx), dyb = sub_rn(p.w, sy);
        const u64 kb = mkkey(add_rn(mul_rn(dxb, dxb), mul_rn(dyb, dyb)), j + 1);
        if (ka < key) key = ka;
        if (kb < key) key = kb;
      }
      #pragma unroll
      for (int m = 32; m >= 1; m >>= 1) {
        const u64 ok = __shfl_xor(key, m, 64);
        if (ok < key) key = ok;
      }
      if (lane == 0) sharedK[wave] = key;
      __syncthreads();

      // ---- incremental epoch-gated tail: wave 0 only ----
      if (wave == 0) {
        u64 kk = (lane < 4) ? sharedK[lane] : KEY_MAX;
        u64 ok = __shfl_xor(kk, 1, 64); if (ok < kk) kk = ok;
        ok = __shfl_xor(kk, 2, 64);     if (ok < kk) kk = ok;

        if (k >= 1) {   // fold the 64 fresh nodes (cb+1 .. c), one per lane
          while (ld_agent32(nflag) < (unsigned)k) __builtin_amdgcn_s_sleep(1);
          compiler_fence();
          const int j = cb + 1 + lane;
          const u64 nv = ld_agent(&outU[j]);
          const float px = __uint_as_float((unsigned)(nv & 0xffffffffu));
          const float py = __uint_as_float((unsigned)(nv >> 32));
          float2 p; p.x = px; p.y = py;
          nodesL[j - 1] = p;            // stage for future bulk scans
          const float dx = sub_rn(px, sx), dy = sub_rn(py, sy);
          const u64 ki = mkkey(add_rn(mul_rn(dx, dx), mul_rn(dy, dy)), j);
          if (ki < kk) kk = ki;         // (d2,idx) key: tie-break order-free
        }
        #pragma unroll
        for (int m = 32; m >= 1; m >>= 1) {
          const u64 o2 = __shfl_xor(kk, m, 64);
          if (o2 < kk) kk = o2;
        }
        if (lane == 0) {
          st_agent(&MbufK[b], kk | ((u64)(unsigned)(k + 1) << 13));
        }
      }
      // gate: next iter's bulk reads include the nodes wave 0 just wrote;
      // sharedK is also reused next iter.
      __syncthreads();
    }
  }
}

extern "C" void kernel_launch(void* const* d_in, const int* in_sizes, int n_in,
                              void* d_out, int out_size, void* d_ws, size_t ws_size,
                              hipStream_t stream) {
  const float* state = (const float*)d_in[0];
  const float* goal  = (const float*)d_in[1];
  const float* u     = (const float*)d_in[2];
  const float* r     = (const float*)d_in[3];
  float* out = (float*)d_out;
  unsigned* ws = (unsigned*)d_ws;
  (void)in_sizes; (void)n_in; (void)out_size; (void)ws_size;
  rrt_kernel<<<NSCAN + 1, NTHREADS, 0, stream>>>(state, goal, u, r, out, ws);
}